// Round 5
// baseline (162.156 us; speedup 1.0000x reference)
//
#include <hip/hip_runtime.h>
#include <hip/hip_bf16.h>

#define HW 65536

typedef short short8 __attribute__((ext_vector_type(8)));
typedef float f32x4 __attribute__((ext_vector_type(4)));

__device__ __forceinline__ unsigned short f2bf(float x) {
    return __builtin_bit_cast(unsigned short, __float2bfloat16(x));
}
__device__ __forceinline__ f32x4 mfma16(short8 a, short8 b, f32x4 c) {
    return __builtin_amdgcn_mfma_f32_16x16x32_bf16(a, b, c, 0, 0, 0);
}

// ---------------- weight prep (one block) ----------------
// wpack (bf16): [0]Wql'(64x64, W*lnw) [4096]Wqr [8192]Wvl [10240]Wvr
//               [12288]Wrl [14336]Wrr    st (f32): s[64], t[64]
__global__ __launch_bounds__(256) void prep_kernel(
    const float* __restrict__ wl1, const float* __restrict__ bl1,
    const float* __restrict__ wr1,
    const float* __restrict__ wl2, const float* __restrict__ wr2,
    const float* __restrict__ wlres, const float* __restrict__ wrres,
    const float* __restrict__ lnw, const float* __restrict__ lnb,
    __hip_bfloat16* __restrict__ wpack, float* __restrict__ st)
{
    const int tid = threadIdx.x;
    if (tid < 64) {
        const int o = tid;
        float s = 0.f, t = 0.f;
        for (int c = 0; c < 64; ++c) {
            __hip_bfloat16 wb = __float2bfloat16(wl1[o*64+c] * lnw[c]);
            wpack[o*64+c] = wb;
            s += __bfloat162float(wb);
            t += wl1[o*64+c] * lnb[c];
        }
        st[o] = s;
        st[64+o] = t + bl1[o];
    } else if (tid < 128) {
        const int o = tid - 64;
        for (int c = 0; c < 64; ++c) wpack[4096 + o*64+c] = __float2bfloat16(wr1[o*64+c]);
    } else if (tid < 160) {
        const int o = tid - 128;
        for (int c = 0; c < 64; ++c) wpack[8192 + o*64+c] = __float2bfloat16(wl2[o*64+c]);
    } else if (tid < 192) {
        const int o = tid - 160;
        for (int c = 0; c < 64; ++c) wpack[10240 + o*64+c] = __float2bfloat16(wr2[o*64+c]);
    } else if (tid < 224) {
        const int o = tid - 192;
        for (int c = 0; c < 64; ++c) wpack[12288 + o*64+c] = __float2bfloat16(wlres[o*64+c]);
    } else {
        const int o = tid - 224;
        for (int c = 0; c < 64; ++c) wpack[14336 + o*64+c] = __float2bfloat16(wrres[o*64+c]);
    }
}

// ---------------- fused proj + bidirectional attention ----------------
// LDS: QL[0,32K) QR[32K,64K) VL[64K,80K) VR[80K,96K) X/P[96K,128K) AUX[128K..)
//   q: px-major [256px][64ch] bf16, 16B-block cb at px*8 + (cb^(px&7))
//   v: ch-major [32ch][256px] bf16, 16B-block vb at ch*32 + (vb^(ch&7))
//   P: per-wave 2K, [16 row][64 key] bf16, block pb at row*8 + (pb^(row&7))
#define QL_OFF 0
#define QR_OFF 32768
#define VL_OFF 65536
#define VR_OFF 81920
#define XP_OFF 98304
#define AUX_OFF 131072
#define SMEM_BYTES (131072 + 11776)

__global__ __launch_bounds__(1024, 4) void fused_kernel(
    const float* __restrict__ xg_l, const float* __restrict__ xg_r,
    const __hip_bfloat16* __restrict__ wpack, const float* __restrict__ st,
    const float* __restrict__ bqr_g, const float* __restrict__ bl2,
    const float* __restrict__ br2, const float* __restrict__ blres,
    const float* __restrict__ brres, const float* __restrict__ beta,
    const float* __restrict__ gamma, float* __restrict__ out)
{
    __shared__ __align__(16) unsigned char smem[SMEM_BYTES];

    const int bh = blockIdx.x;
    const int b = bh >> 8, h = bh & 255;
    const int tid = threadIdx.x;
    const int wv = tid >> 6, lane = tid & 63;
    const int g = lane >> 4, lr = lane & 15;
    const int px = tid & 255, quarter = tid >> 8;   // 4 quarters x 256 px

    float* aArr  = (float*)(smem + AUX_OFF);          // rstd per px (1K)
    float* bbArr = (float*)(smem + AUX_OFF + 1024);   // -rstd*mu per px (1K)
    float* sArr  = (float*)(smem + AUX_OFF + 2048);
    float* tArr  = (float*)(smem + AUX_OFF + 2304);
    float* bqrA  = (float*)(smem + AUX_OFF + 2560);
    float* bvA   = (float*)(smem + AUX_OFF + 2816);
    float* bresA = (float*)(smem + AUX_OFF + 3072);
    float* coefA = (float*)(smem + AUX_OFF + 3328);
    float* pS    = (float*)(smem + AUX_OFF + 3584);   // 4K: [4][256]
    float* pQ    = (float*)(smem + AUX_OFF + 7680);   // 4K: [4][256]

    const size_t obase = (size_t)b * 64 * HW + (size_t)h * 256;
    const size_t xbase = obase + px;

    // ---- each thread loads 16 channels of both x rows (coalesced) ----
    float xl[16], xr_[16];
#pragma unroll
    for (int c = 0; c < 16; ++c) xl[c] = xg_l[xbase + (size_t)(quarter*16 + c) * HW];
#pragma unroll
    for (int c = 0; c < 16; ++c) xr_[c] = xg_r[xbase + (size_t)(quarter*16 + c) * HW];

    if (tid < 64) {
        sArr[tid] = st[tid];
        tArr[tid] = st[64 + tid];
        bqrA[tid] = bqr_g[tid];
        bvA[tid]  = tid < 32 ? bl2[tid]   : br2[tid - 32];
        bresA[tid]= tid < 32 ? blres[tid] : brres[tid - 32];
        coefA[tid]= tid < 32 ? beta[tid]  : gamma[tid - 32];
    }

    // ---- LN partial stats for left row ----
    {
        float s = 0.f, q = 0.f;
#pragma unroll
        for (int c = 0; c < 16; ++c) { s += xl[c]; q = fmaf(xl[c], xl[c], q); }
        pS[quarter*256 + px] = s;
        pQ[quarter*256 + px] = q;
    }

    // ---- stage X_left px-major bf16 swizzled (this thread's 16 ch) ----
    uint4* X16 = (uint4*)(smem + XP_OFF);
#pragma unroll
    for (int cb = 0; cb < 2; ++cb) {
        uint4 u;
        u.x = f2bf(xl[cb*8+0]) | ((unsigned)f2bf(xl[cb*8+1]) << 16);
        u.y = f2bf(xl[cb*8+2]) | ((unsigned)f2bf(xl[cb*8+3]) << 16);
        u.z = f2bf(xl[cb*8+4]) | ((unsigned)f2bf(xl[cb*8+5]) << 16);
        u.w = f2bf(xl[cb*8+6]) | ((unsigned)f2bf(xl[cb*8+7]) << 16);
        X16[px*8 + ((quarter*2 + cb) ^ (px & 7))] = u;
    }
    __syncthreads();
    if (quarter == 0) {
        float s = pS[px] + pS[256 + px] + pS[512 + px] + pS[768 + px];
        float q = pQ[px] + pQ[256 + px] + pQ[512 + px] + pQ[768 + px];
        float mu = s * (1.f / 64.f);
        float var = q * (1.f / 64.f) - mu * mu;
        float rstd = rsqrtf(var + 1e-6f);
        aArr[px] = rstd;
        bbArr[px] = -rstd * mu;
    }
    __syncthreads();

    const uint4* W16 = (const uint4*)wpack;

    // proj one side: q (4 Mtiles), v (2), res (2) over this wave's 1 px-tile
    auto proj_side = [&](int wq, int wvv, int wr, unsigned char* qdst,
                         unsigned char* vdst, int chbase, bool ln) {
        const int p = wv*16 + lr;
        short8 bfr0 = __builtin_bit_cast(short8, X16[p*8 + (g ^ (p&7))]);
        short8 bfr1 = __builtin_bit_cast(short8, X16[p*8 + ((4+g) ^ (p&7))]);
        // ---- q: D[ch][px] ----
#pragma unroll
        for (int ot = 0; ot < 4; ++ot) {
            const int out0 = ot * 16;
            short8 af0 = __builtin_bit_cast(short8, W16[wq + (out0+lr)*8 + g]);
            short8 af1 = __builtin_bit_cast(short8, W16[wq + (out0+lr)*8 + 4 + g]);
            const int ch0 = out0 + 4*g;
            f32x4 c1 = *(const f32x4*)&(ln ? sArr : bqrA)[ch0];
            f32x4 c2 = ln ? *(const f32x4*)&tArr[ch0] : (f32x4){0.f,0.f,0.f,0.f};
            f32x4 acc = {0.f,0.f,0.f,0.f};
            acc = mfma16(af0, bfr0, acc);
            acc = mfma16(af1, bfr1, acc);
            float q0,q1,q2,q3;
            if (ln) {
                const float a_ = aArr[p], b_ = bbArr[p];
                q0 = fmaf(a_, acc[0], fmaf(b_, c1[0], c2[0]));
                q1 = fmaf(a_, acc[1], fmaf(b_, c1[1], c2[1]));
                q2 = fmaf(a_, acc[2], fmaf(b_, c1[2], c2[2]));
                q3 = fmaf(a_, acc[3], fmaf(b_, c1[3], c2[3]));
            } else {
                q0 = acc[0]+c1[0]; q1 = acc[1]+c1[1];
                q2 = acc[2]+c1[2]; q3 = acc[3]+c1[3];
            }
            unsigned lo = f2bf(q0) | ((unsigned)f2bf(q1) << 16);
            unsigned hi = f2bf(q2) | ((unsigned)f2bf(q3) << 16);
            *(uint2*)(qdst + p*128 + (((ch0>>3) ^ (p&7))*16) + (ch0&7)*2)
                = make_uint2(lo, hi);
        }
        // ---- v: swapped operands -> D[px][ch], 8B store ----
#pragma unroll
        for (int ot = 0; ot < 2; ++ot) {
            const int out0 = ot * 16;
            short8 af0 = __builtin_bit_cast(short8, W16[wvv + (out0+lr)*8 + g]);
            short8 af1 = __builtin_bit_cast(short8, W16[wvv + (out0+lr)*8 + 4 + g]);
            const int ch = out0 + lr;               // this lane's channel
            const float bv = bvA[chbase + ch];
            f32x4 acc = {0.f,0.f,0.f,0.f};
            acc = mfma16(bfr0, af0, acc);
            acc = mfma16(bfr1, af1, acc);
            // lane holds px = wv*16 + 4g + r for r=0..3
            unsigned lo = f2bf(acc[0]+bv) | ((unsigned)f2bf(acc[1]+bv) << 16);
            unsigned hi = f2bf(acc[2]+bv) | ((unsigned)f2bf(acc[3]+bv) << 16);
            const int vb = wv*2 + (g>>1);
            *(uint2*)(vdst + ch*512 + ((vb ^ (ch&7))*16) + (g&1)*8)
                = make_uint2(lo, hi);
        }
        // ---- res -> global: D[ch][px] ----
#pragma unroll
        for (int ot = 0; ot < 2; ++ot) {
            const int out0 = ot * 16;
            short8 af0 = __builtin_bit_cast(short8, W16[wr + (out0+lr)*8 + g]);
            short8 af1 = __builtin_bit_cast(short8, W16[wr + (out0+lr)*8 + 4 + g]);
            const int ch0 = out0 + 4*g;
            f32x4 bz = *(const f32x4*)&bresA[chbase + ch0];
            f32x4 acc = {0.f,0.f,0.f,0.f};
            acc = mfma16(af0, bfr0, acc);
            acc = mfma16(af1, bfr1, acc);
            float* op = out + obase + p + (size_t)(chbase + ch0) * HW;
#pragma unroll
            for (int r = 0; r < 4; ++r) op[(size_t)r * HW] = acc[r] + bz[r];
        }
    };

    proj_side(0, 1024, 1536, smem + QL_OFF, smem + VL_OFF, 0, true);
    __syncthreads();

    // ---- stage X_right ----
#pragma unroll
    for (int cb = 0; cb < 2; ++cb) {
        uint4 u;
        u.x = f2bf(xr_[cb*8+0]) | ((unsigned)f2bf(xr_[cb*8+1]) << 16);
        u.y = f2bf(xr_[cb*8+2]) | ((unsigned)f2bf(xr_[cb*8+3]) << 16);
        u.z = f2bf(xr_[cb*8+4]) | ((unsigned)f2bf(xr_[cb*8+5]) << 16);
        u.w = f2bf(xr_[cb*8+6]) | ((unsigned)f2bf(xr_[cb*8+7]) << 16);
        X16[px*8 + ((quarter*2 + cb) ^ (px & 7))] = u;
    }
    __syncthreads();

    proj_side(512, 1280, 1792, smem + QR_OFF, smem + VR_OFF, 32, false);
    __syncthreads();   // all q/v in LDS, res stores issued; X region becomes P

    // ------- attention: waves 0-7 dir0, waves 8-15 dir1; 2 chunks each -------
    unsigned char* Pw = smem + XP_OFF + wv * 2048;
    const int dir = wv >> 3, wsub = wv & 7;
    const float cs = 0.125f * 1.44269504088896f;   // scale * log2(e)

    const uint4* Q16 = (const uint4*)(smem + (dir ? QR_OFF : QL_OFF));
    const uint4* K16 = (const uint4*)(smem + (dir ? QL_OFF : QR_OFF));
    const uint4* V16 = (const uint4*)(smem + (dir ? VL_OFF : VR_OFF));
    const float* coef = coefA + dir * 32;

    for (int c = 0; c < 2; ++c) {
        const int row0 = c * 128 + wsub * 16;
        const int qpx = row0 + lr;
        short8 qf0 = __builtin_bit_cast(short8, Q16[qpx*8 + (g ^ (qpx&7))]);
        short8 qf1 = __builtin_bit_cast(short8, Q16[qpx*8 + ((4+g) ^ (qpx&7))]);

        f32x4 sacc[16];
#pragma unroll
        for (int t = 0; t < 16; ++t) sacc[t] = (f32x4){0.f,0.f,0.f,0.f};
        __builtin_amdgcn_s_setprio(1);
#pragma unroll
        for (int t = 0; t < 16; ++t) {
            const int key = t * 16 + lr;
            const int sw = key & 7;
            short8 a0 = __builtin_bit_cast(short8, K16[key*8 + (g ^ sw)]);
            short8 a1 = __builtin_bit_cast(short8, K16[key*8 + ((4+g) ^ sw)]);
            sacc[t] = mfma16(a0, qf0, sacc[t]);
            sacc[t] = mfma16(a1, qf1, sacc[t]);
        }
        __builtin_amdgcn_s_setprio(0);
        // lane holds S^T[key = 16t + 4g + r][q-row = lr]
        float mx = -3.0e38f;
#pragma unroll
        for (int t = 0; t < 16; ++t)
            mx = fmaxf(mx, fmaxf(fmaxf(sacc[t][0], sacc[t][1]),
                                 fmaxf(sacc[t][2], sacc[t][3])));
        mx = fmaxf(mx, __shfl_xor(mx, 16));
        mx = fmaxf(mx, __shfl_xor(mx, 32));

        float lsum = 0.f;
        f32x4 o0 = (f32x4){0.f,0.f,0.f,0.f};
        f32x4 o1 = (f32x4){0.f,0.f,0.f,0.f};
#pragma unroll
        for (int hh = 0; hh < 4; ++hh) {
            // exp + pack + write this quarter's P (16 rows x 64 keys, 2K)
#pragma unroll
            for (int t8 = 0; t8 < 4; ++t8) {
                const int t16 = hh * 4 + t8;
                float p0 = exp2f((sacc[t16][0] - mx) * cs);
                float p1 = exp2f((sacc[t16][1] - mx) * cs);
                float p2 = exp2f((sacc[t16][2] - mx) * cs);
                float p3 = exp2f((sacc[t16][3] - mx) * cs);
                lsum += (p0 + p1) + (p2 + p3);
                unsigned lo = f2bf(p0) | ((unsigned)f2bf(p1) << 16);
                unsigned hi = f2bf(p2) | ((unsigned)f2bf(p3) << 16);
                int pb = (2*t8 + (g >> 1)) ^ (lr & 7);
                *(uint2*)(Pw + lr*128 + pb*16 + (g & 1)*8) = make_uint2(lo, hi);
            }
            // PV over this quarter's 64 keys
#pragma unroll
            for (int t = 0; t < 2; ++t) {
                const int pb = 4*t + g;
                const int vb = 8*hh + 4*t + g;
                short8 pa = __builtin_bit_cast(short8,
                            *(const uint4*)(Pw + lr*128 + ((pb ^ (lr&7))*16)));
                short8 v0 = __builtin_bit_cast(short8, V16[lr*32 + (vb ^ (lr&7))]);
                short8 v1 = __builtin_bit_cast(short8, V16[(16+lr)*32 + (vb ^ (lr&7))]);
                o0 = mfma16(pa, v0, o0);
                o1 = mfma16(pa, v1, o1);
            }
        }
        lsum += __shfl_xor(lsum, 16);
        lsum += __shfl_xor(lsum, 32);
        const float inv = 1.f / lsum;

        // transpose O through (dead) P in two 16-ch passes, coalesced += to out
        float* Ot = (float*)Pw;   // [16 ch][17] f32 = 1088B <= 2048B
        float* outp = out + obase + (size_t)(dir*32) * HW + row0 + lr;
#pragma unroll
        for (int r = 0; r < 4; ++r) Ot[lr*17 + (g*4 + r)] = o0[r];
#pragma unroll
        for (int it = 0; it < 4; ++it) {
            const int ch = it*4 + g;
            outp[(size_t)ch * HW] += Ot[ch*17 + lr] * inv * coef[ch];
        }
#pragma unroll
        for (int r = 0; r < 4; ++r) Ot[lr*17 + (g*4 + r)] = o1[r];
#pragma unroll
        for (int it = 0; it < 4; ++it) {
            const int ch = it*4 + g;
            outp[(size_t)(16 + ch) * HW] += Ot[ch*17 + lr] * inv * coef[16 + ch];
        }
    }
}

extern "C" void kernel_launch(void* const* d_in, const int* in_sizes, int n_in,
                              void* d_out, int out_size, void* d_ws, size_t ws_size,
                              hipStream_t stream) {
    (void)in_sizes; (void)n_in; (void)out_size; (void)ws_size;
    const float* xr    = (const float*)d_in[0];
    const float* xh    = (const float*)d_in[1];
    const float* lnw   = (const float*)d_in[2];
    const float* lnb   = (const float*)d_in[3];
    const float* wl1   = (const float*)d_in[4];
    const float* bl1   = (const float*)d_in[5];
    const float* wr1   = (const float*)d_in[6];
    const float* br1   = (const float*)d_in[7];
    const float* wl2   = (const float*)d_in[8];
    const float* bl2   = (const float*)d_in[9];
    const float* wr2   = (const float*)d_in[10];
    const float* br2   = (const float*)d_in[11];
    const float* wlres = (const float*)d_in[12];
    const float* blres = (const float*)d_in[13];
    const float* wrres = (const float*)d_in[14];
    const float* brres = (const float*)d_in[15];
    const float* beta  = (const float*)d_in[16];
    const float* gamma = (const float*)d_in[17];
    float* out = (float*)d_out;

    __hip_bfloat16* wpack = (__hip_bfloat16*)d_ws;
    float* st = (float*)((unsigned char*)d_ws + 32768);

    prep_kernel<<<dim3(1), dim3(256), 0, stream>>>(
        wl1, bl1, wr1, wl2, wr2, wlres, wrres, lnw, lnb, wpack, st);
    fused_kernel<<<dim3(1024), dim3(1024), 0, stream>>>(
        xr, xh, wpack, st, br1, bl2, br2, blres, brres, beta, gamma, out);
}

// Round 6
// 161.271 us; speedup vs baseline: 1.0055x; 1.0055x over previous
//
#include <hip/hip_runtime.h>
#include <hip/hip_bf16.h>

#define HW 65536

typedef short short8 __attribute__((ext_vector_type(8)));
typedef float f32x4 __attribute__((ext_vector_type(4)));

__device__ __forceinline__ unsigned short f2bf(float x) {
    return __builtin_bit_cast(unsigned short, __float2bfloat16(x));
}
__device__ __forceinline__ f32x4 mfma16(short8 a, short8 b, f32x4 c) {
    return __builtin_amdgcn_mfma_f32_16x16x32_bf16(a, b, c, 0, 0, 0);
}

// ---------------- weight prep (one block) ----------------
// wpack (bf16): [0]Wql'(64x64, W*lnw) [4096]Wqr [8192]Wvl [10240]Wvr
//               [12288]Wrl [14336]Wrr    st (f32): s[64], t[64]
__global__ __launch_bounds__(256) void prep_kernel(
    const float* __restrict__ wl1, const float* __restrict__ bl1,
    const float* __restrict__ wr1,
    const float* __restrict__ wl2, const float* __restrict__ wr2,
    const float* __restrict__ wlres, const float* __restrict__ wrres,
    const float* __restrict__ lnw, const float* __restrict__ lnb,
    __hip_bfloat16* __restrict__ wpack, float* __restrict__ st)
{
    const int tid = threadIdx.x;
    if (tid < 64) {
        const int o = tid;
        float s = 0.f, t = 0.f;
        for (int c = 0; c < 64; ++c) {
            __hip_bfloat16 wb = __float2bfloat16(wl1[o*64+c] * lnw[c]);
            wpack[o*64+c] = wb;
            s += __bfloat162float(wb);
            t += wl1[o*64+c] * lnb[c];
        }
        st[o] = s;
        st[64+o] = t + bl1[o];
    } else if (tid < 128) {
        const int o = tid - 64;
        for (int c = 0; c < 64; ++c) wpack[4096 + o*64+c] = __float2bfloat16(wr1[o*64+c]);
    } else if (tid < 160) {
        const int o = tid - 128;
        for (int c = 0; c < 64; ++c) wpack[8192 + o*64+c] = __float2bfloat16(wl2[o*64+c]);
    } else if (tid < 192) {
        const int o = tid - 160;
        for (int c = 0; c < 64; ++c) wpack[10240 + o*64+c] = __float2bfloat16(wr2[o*64+c]);
    } else if (tid < 224) {
        const int o = tid - 192;
        for (int c = 0; c < 64; ++c) wpack[12288 + o*64+c] = __float2bfloat16(wlres[o*64+c]);
    } else {
        const int o = tid - 224;
        for (int c = 0; c < 64; ++c) wpack[14336 + o*64+c] = __float2bfloat16(wrres[o*64+c]);
    }
}

// ---------------- fused proj + bidirectional attention ----------------
// LDS: QL[0,32K) QR[32K,64K) VL[64K,80K) VR[80K,96K) X/P[96K,128K) AUX[128K..)
//   q: px-major [256px][64ch] bf16, 16B-block cb at px*8 + (cb^(px&7))
//   v: ch-major [32ch][256px] bf16, 16B-block vb at ch*32 + (vb^(ch&7))
//   P: per-wave 2K, [16 row][64 key] bf16, block pb at row*8 + (pb^(row&7))
#define QL_OFF 0
#define QR_OFF 32768
#define VL_OFF 65536
#define VR_OFF 81920
#define XP_OFF 98304
#define AUX_OFF 131072
#define SMEM_BYTES (131072 + 11776)

__global__ __launch_bounds__(1024) void fused_kernel(
    const float* __restrict__ xg_l, const float* __restrict__ xg_r,
    const __hip_bfloat16* __restrict__ wpack, const float* __restrict__ st,
    const float* __restrict__ bqr_g, const float* __restrict__ bl2,
    const float* __restrict__ br2, const float* __restrict__ blres,
    const float* __restrict__ brres, const float* __restrict__ beta,
    const float* __restrict__ gamma, float* __restrict__ out)
{
    __shared__ __align__(16) unsigned char smem[SMEM_BYTES];

    const int bh = blockIdx.x;
    const int b = bh >> 8, h = bh & 255;
    const int tid = threadIdx.x;
    const int wv = tid >> 6, lane = tid & 63;
    const int g = lane >> 4, lr = lane & 15;
    const int px = tid & 255, quarter = tid >> 8;   // 4 quarters x 256 px

    float* aArr  = (float*)(smem + AUX_OFF);          // rstd per px (1K)
    float* bbArr = (float*)(smem + AUX_OFF + 1024);   // -rstd*mu per px (1K)
    float* sArr  = (float*)(smem + AUX_OFF + 2048);
    float* tArr  = (float*)(smem + AUX_OFF + 2304);
    float* bqrA  = (float*)(smem + AUX_OFF + 2560);
    float* bvA   = (float*)(smem + AUX_OFF + 2816);
    float* bresA = (float*)(smem + AUX_OFF + 3072);
    float* coefA = (float*)(smem + AUX_OFF + 3328);
    float* pS    = (float*)(smem + AUX_OFF + 3584);   // 4K: [4][256]
    float* pQ    = (float*)(smem + AUX_OFF + 7680);   // 4K: [4][256]

    const size_t obase = (size_t)b * 64 * HW + (size_t)h * 256;
    const size_t xbase = obase + px;

    // ---- each thread loads 16 channels of both x rows (coalesced) ----
    float xl[16], xr_[16];
#pragma unroll
    for (int c = 0; c < 16; ++c) xl[c] = xg_l[xbase + (size_t)(quarter*16 + c) * HW];
#pragma unroll
    for (int c = 0; c < 16; ++c) xr_[c] = xg_r[xbase + (size_t)(quarter*16 + c) * HW];

    if (tid < 64) {
        sArr[tid] = st[tid];
        tArr[tid] = st[64 + tid];
        bqrA[tid] = bqr_g[tid];
        bvA[tid]  = tid < 32 ? bl2[tid]   : br2[tid - 32];
        bresA[tid]= tid < 32 ? blres[tid] : brres[tid - 32];
        coefA[tid]= tid < 32 ? beta[tid]  : gamma[tid - 32];
    }

    // ---- LN partial stats for left row ----
    {
        float s = 0.f, q = 0.f;
#pragma unroll
        for (int c = 0; c < 16; ++c) { s += xl[c]; q = fmaf(xl[c], xl[c], q); }
        pS[quarter*256 + px] = s;
        pQ[quarter*256 + px] = q;
    }

    // ---- stage X_left px-major bf16 swizzled (this thread's 16 ch) ----
    uint4* X16 = (uint4*)(smem + XP_OFF);
#pragma unroll
    for (int cb = 0; cb < 2; ++cb) {
        uint4 u;
        u.x = f2bf(xl[cb*8+0]) | ((unsigned)f2bf(xl[cb*8+1]) << 16);
        u.y = f2bf(xl[cb*8+2]) | ((unsigned)f2bf(xl[cb*8+3]) << 16);
        u.z = f2bf(xl[cb*8+4]) | ((unsigned)f2bf(xl[cb*8+5]) << 16);
        u.w = f2bf(xl[cb*8+6]) | ((unsigned)f2bf(xl[cb*8+7]) << 16);
        X16[px*8 + ((quarter*2 + cb) ^ (px & 7))] = u;
    }
    __syncthreads();
    if (quarter == 0) {
        float s = pS[px] + pS[256 + px] + pS[512 + px] + pS[768 + px];
        float q = pQ[px] + pQ[256 + px] + pQ[512 + px] + pQ[768 + px];
        float mu = s * (1.f / 64.f);
        float var = q * (1.f / 64.f) - mu * mu;
        float rstd = rsqrtf(var + 1e-6f);
        aArr[px] = rstd;
        bbArr[px] = -rstd * mu;
    }
    __syncthreads();

    const uint4* W16 = (const uint4*)wpack;

    // proj one side: q (4 Mtiles), v (2), res (2) over this wave's 1 px-tile
    auto proj_side = [&](int wq, int wvv, int wr, unsigned char* qdst,
                         unsigned char* vdst, int chbase, bool ln) {
        const int p = wv*16 + lr;
        short8 bfr0 = __builtin_bit_cast(short8, X16[p*8 + (g ^ (p&7))]);
        short8 bfr1 = __builtin_bit_cast(short8, X16[p*8 + ((4+g) ^ (p&7))]);
        // ---- q: D[ch][px] ----
#pragma unroll
        for (int ot = 0; ot < 4; ++ot) {
            const int out0 = ot * 16;
            short8 af0 = __builtin_bit_cast(short8, W16[wq + (out0+lr)*8 + g]);
            short8 af1 = __builtin_bit_cast(short8, W16[wq + (out0+lr)*8 + 4 + g]);
            const int ch0 = out0 + 4*g;
            f32x4 c1 = *(const f32x4*)&(ln ? sArr : bqrA)[ch0];
            f32x4 c2 = ln ? *(const f32x4*)&tArr[ch0] : (f32x4){0.f,0.f,0.f,0.f};
            f32x4 acc = {0.f,0.f,0.f,0.f};
            acc = mfma16(af0, bfr0, acc);
            acc = mfma16(af1, bfr1, acc);
            float q0,q1,q2,q3;
            if (ln) {
                const float a_ = aArr[p], b_ = bbArr[p];
                q0 = fmaf(a_, acc[0], fmaf(b_, c1[0], c2[0]));
                q1 = fmaf(a_, acc[1], fmaf(b_, c1[1], c2[1]));
                q2 = fmaf(a_, acc[2], fmaf(b_, c1[2], c2[2]));
                q3 = fmaf(a_, acc[3], fmaf(b_, c1[3], c2[3]));
            } else {
                q0 = acc[0]+c1[0]; q1 = acc[1]+c1[1];
                q2 = acc[2]+c1[2]; q3 = acc[3]+c1[3];
            }
            unsigned lo = f2bf(q0) | ((unsigned)f2bf(q1) << 16);
            unsigned hi = f2bf(q2) | ((unsigned)f2bf(q3) << 16);
            *(uint2*)(qdst + p*128 + (((ch0>>3) ^ (p&7))*16) + (ch0&7)*2)
                = make_uint2(lo, hi);
        }
        // ---- v: swapped operands -> D[px][ch], 8B store ----
#pragma unroll
        for (int ot = 0; ot < 2; ++ot) {
            const int out0 = ot * 16;
            short8 af0 = __builtin_bit_cast(short8, W16[wvv + (out0+lr)*8 + g]);
            short8 af1 = __builtin_bit_cast(short8, W16[wvv + (out0+lr)*8 + 4 + g]);
            const int ch = out0 + lr;               // this lane's channel
            const float bv = bvA[chbase + ch];
            f32x4 acc = {0.f,0.f,0.f,0.f};
            acc = mfma16(bfr0, af0, acc);
            acc = mfma16(bfr1, af1, acc);
            // lane holds px = wv*16 + 4g + r for r=0..3
            unsigned lo = f2bf(acc[0]+bv) | ((unsigned)f2bf(acc[1]+bv) << 16);
            unsigned hi = f2bf(acc[2]+bv) | ((unsigned)f2bf(acc[3]+bv) << 16);
            const int vb = wv*2 + (g>>1);
            *(uint2*)(vdst + ch*512 + ((vb ^ (ch&7))*16) + (g&1)*8)
                = make_uint2(lo, hi);
        }
        // ---- res -> global: D[ch][px] ----
#pragma unroll
        for (int ot = 0; ot < 2; ++ot) {
            const int out0 = ot * 16;
            short8 af0 = __builtin_bit_cast(short8, W16[wr + (out0+lr)*8 + g]);
            short8 af1 = __builtin_bit_cast(short8, W16[wr + (out0+lr)*8 + 4 + g]);
            const int ch0 = out0 + 4*g;
            f32x4 bz = *(const f32x4*)&bresA[chbase + ch0];
            f32x4 acc = {0.f,0.f,0.f,0.f};
            acc = mfma16(af0, bfr0, acc);
            acc = mfma16(af1, bfr1, acc);
            float* op = out + obase + p + (size_t)(chbase + ch0) * HW;
#pragma unroll
            for (int r = 0; r < 4; ++r) op[(size_t)r * HW] = acc[r] + bz[r];
        }
    };

    proj_side(0, 1024, 1536, smem + QL_OFF, smem + VL_OFF, 0, true);
    __syncthreads();

    // ---- stage X_right ----
#pragma unroll
    for (int cb = 0; cb < 2; ++cb) {
        uint4 u;
        u.x = f2bf(xr_[cb*8+0]) | ((unsigned)f2bf(xr_[cb*8+1]) << 16);
        u.y = f2bf(xr_[cb*8+2]) | ((unsigned)f2bf(xr_[cb*8+3]) << 16);
        u.z = f2bf(xr_[cb*8+4]) | ((unsigned)f2bf(xr_[cb*8+5]) << 16);
        u.w = f2bf(xr_[cb*8+6]) | ((unsigned)f2bf(xr_[cb*8+7]) << 16);
        X16[px*8 + ((quarter*2 + cb) ^ (px & 7))] = u;
    }
    __syncthreads();

    proj_side(512, 1280, 1792, smem + QR_OFF, smem + VR_OFF, 32, false);
    __syncthreads();   // all q/v in LDS, res stores issued; X region becomes P

    // ------- attention: waves 0-7 dir0, waves 8-15 dir1; 2 chunks each -------
    unsigned char* Pw = smem + XP_OFF + wv * 2048;
    const int dir = wv >> 3, wsub = wv & 7;
    const float cs = 0.125f * 1.44269504088896f;   // scale * log2(e)

    const uint4* Q16 = (const uint4*)(smem + (dir ? QR_OFF : QL_OFF));
    const uint4* K16 = (const uint4*)(smem + (dir ? QL_OFF : QR_OFF));
    const uint4* V16 = (const uint4*)(smem + (dir ? VL_OFF : VR_OFF));
    const float* coef = coefA + dir * 32;

    for (int c = 0; c < 2; ++c) {
        const int row0 = c * 128 + wsub * 16;
        const int qpx = row0 + lr;
        short8 qf0 = __builtin_bit_cast(short8, Q16[qpx*8 + (g ^ (qpx&7))]);
        short8 qf1 = __builtin_bit_cast(short8, Q16[qpx*8 + ((4+g) ^ (qpx&7))]);

        f32x4 sacc[16];
#pragma unroll
        for (int t = 0; t < 16; ++t) sacc[t] = (f32x4){0.f,0.f,0.f,0.f};
        __builtin_amdgcn_s_setprio(1);
#pragma unroll
        for (int t = 0; t < 16; ++t) {
            const int key = t * 16 + lr;
            const int sw = key & 7;
            short8 a0 = __builtin_bit_cast(short8, K16[key*8 + (g ^ sw)]);
            short8 a1 = __builtin_bit_cast(short8, K16[key*8 + ((4+g) ^ sw)]);
            sacc[t] = mfma16(a0, qf0, sacc[t]);
            sacc[t] = mfma16(a1, qf1, sacc[t]);
        }
        __builtin_amdgcn_s_setprio(0);
        // lane holds S^T[key = 16t + 4g + r][q-row = lr]
        float mx = -3.0e38f;
#pragma unroll
        for (int t = 0; t < 16; ++t)
            mx = fmaxf(mx, fmaxf(fmaxf(sacc[t][0], sacc[t][1]),
                                 fmaxf(sacc[t][2], sacc[t][3])));
        mx = fmaxf(mx, __shfl_xor(mx, 16));
        mx = fmaxf(mx, __shfl_xor(mx, 32));

        float lsum = 0.f;
        f32x4 o0 = (f32x4){0.f,0.f,0.f,0.f};
        f32x4 o1 = (f32x4){0.f,0.f,0.f,0.f};
#pragma unroll
        for (int hh = 0; hh < 4; ++hh) {
            // exp + pack + write this quarter's P (16 rows x 64 keys, 2K)
#pragma unroll
            for (int t8 = 0; t8 < 4; ++t8) {
                const int t16 = hh * 4 + t8;
                float p0 = exp2f((sacc[t16][0] - mx) * cs);
                float p1 = exp2f((sacc[t16][1] - mx) * cs);
                float p2 = exp2f((sacc[t16][2] - mx) * cs);
                float p3 = exp2f((sacc[t16][3] - mx) * cs);
                lsum += (p0 + p1) + (p2 + p3);
                unsigned lo = f2bf(p0) | ((unsigned)f2bf(p1) << 16);
                unsigned hi = f2bf(p2) | ((unsigned)f2bf(p3) << 16);
                int pb = (2*t8 + (g >> 1)) ^ (lr & 7);
                *(uint2*)(Pw + lr*128 + pb*16 + (g & 1)*8) = make_uint2(lo, hi);
            }
            // PV over this quarter's 64 keys
#pragma unroll
            for (int t = 0; t < 2; ++t) {
                const int pb = 4*t + g;
                const int vb = 8*hh + 4*t + g;
                short8 pa = __builtin_bit_cast(short8,
                            *(const uint4*)(Pw + lr*128 + ((pb ^ (lr&7))*16)));
                short8 v0 = __builtin_bit_cast(short8, V16[lr*32 + (vb ^ (lr&7))]);
                short8 v1 = __builtin_bit_cast(short8, V16[(16+lr)*32 + (vb ^ (lr&7))]);
                o0 = mfma16(pa, v0, o0);
                o1 = mfma16(pa, v1, o1);
            }
        }
        lsum += __shfl_xor(lsum, 16);
        lsum += __shfl_xor(lsum, 32);
        const float inv = 1.f / lsum;

        // transpose O through (dead) P in two 16-ch passes, coalesced += to out
        float* Ot = (float*)Pw;   // [16 ch][17] f32 = 1088B <= 2048B
        float* outp = out + obase + (size_t)(dir*32) * HW + row0 + lr;
#pragma unroll
        for (int r = 0; r < 4; ++r) Ot[lr*17 + (g*4 + r)] = o0[r];
#pragma unroll
        for (int it = 0; it < 4; ++it) {
            const int ch = it*4 + g;
            outp[(size_t)ch * HW] += Ot[ch*17 + lr] * inv * coef[ch];
        }
#pragma unroll
        for (int r = 0; r < 4; ++r) Ot[lr*17 + (g*4 + r)] = o1[r];
#pragma unroll
        for (int it = 0; it < 4; ++it) {
            const int ch = it*4 + g;
            outp[(size_t)(16 + ch) * HW] += Ot[ch*17 + lr] * inv * coef[16 + ch];
        }
    }
}

extern "C" void kernel_launch(void* const* d_in, const int* in_sizes, int n_in,
                              void* d_out, int out_size, void* d_ws, size_t ws_size,
                              hipStream_t stream) {
    (void)in_sizes; (void)n_in; (void)out_size; (void)ws_size;
    const float* xr    = (const float*)d_in[0];
    const float* xh    = (const float*)d_in[1];
    const float* lnw   = (const float*)d_in[2];
    const float* lnb   = (const float*)d_in[3];
    const float* wl1   = (const float*)d_in[4];
    const float* bl1   = (const float*)d_in[5];
    const float* wr1   = (const float*)d_in[6];
    const float* br1   = (const float*)d_in[7];
    const float* wl2   = (const float*)d_in[8];
    const float* bl2   = (const float*)d_in[9];
    const float* wr2   = (const float*)d_in[10];
    const float* br2   = (const float*)d_in[11];
    const float* wlres = (const float*)d_in[12];
    const float* blres = (const float*)d_in[13];
    const float* wrres = (const float*)d_in[14];
    const float* brres = (const float*)d_in[15];
    const float* beta  = (const float*)d_in[16];
    const float* gamma = (const float*)d_in[17];
    float* out = (float*)d_out;

    __hip_bfloat16* wpack = (__hip_bfloat16*)d_ws;
    float* st = (float*)((unsigned char*)d_ws + 32768);

    prep_kernel<<<dim3(1), dim3(256), 0, stream>>>(
        wl1, bl1, wr1, wl2, wr2, wlres, wrres, lnw, lnb, wpack, st);
    fused_kernel<<<dim3(1024), dim3(1024), 0, stream>>>(
        xr, xh, wpack, st, br1, bl2, br2, blres, brres, beta, gamma, out);
}

// Round 7
// 147.083 us; speedup vs baseline: 1.1025x; 1.0965x over previous
//
#include <hip/hip_runtime.h>
#include <hip/hip_bf16.h>

#define HW 65536

typedef short short8 __attribute__((ext_vector_type(8)));
typedef float f32x4 __attribute__((ext_vector_type(4)));

__device__ __forceinline__ unsigned short f2bf(float x) {
    return __builtin_bit_cast(unsigned short, __float2bfloat16(x));
}
__device__ __forceinline__ f32x4 mfma16(short8 a, short8 b, f32x4 c) {
    return __builtin_amdgcn_mfma_f32_16x16x32_bf16(a, b, c, 0, 0, 0);
}

// ---------------- weight prep (one block) ----------------
// wpack (bf16): [0]Wql'(64x64, W*lnw) [4096]Wqr [8192]Wvl [10240]Wvr
//               [12288]Wrl [14336]Wrr    st (f32): s[64], t[64]
__global__ __launch_bounds__(256) void prep_kernel(
    const float* __restrict__ wl1, const float* __restrict__ bl1,
    const float* __restrict__ wr1,
    const float* __restrict__ wl2, const float* __restrict__ wr2,
    const float* __restrict__ wlres, const float* __restrict__ wrres,
    const float* __restrict__ lnw, const float* __restrict__ lnb,
    __hip_bfloat16* __restrict__ wpack, float* __restrict__ st)
{
    const int tid = threadIdx.x;
    if (tid < 64) {
        const int o = tid;
        float s = 0.f, t = 0.f;
        for (int c = 0; c < 64; ++c) {
            __hip_bfloat16 wb = __float2bfloat16(wl1[o*64+c] * lnw[c]);
            wpack[o*64+c] = wb;
            s += __bfloat162float(wb);
            t += wl1[o*64+c] * lnb[c];
        }
        st[o] = s;
        st[64+o] = t + bl1[o];
    } else if (tid < 128) {
        const int o = tid - 64;
        for (int c = 0; c < 64; ++c) wpack[4096 + o*64+c] = __float2bfloat16(wr1[o*64+c]);
    } else if (tid < 160) {
        const int o = tid - 128;
        for (int c = 0; c < 64; ++c) wpack[8192 + o*64+c] = __float2bfloat16(wl2[o*64+c]);
    } else if (tid < 192) {
        const int o = tid - 160;
        for (int c = 0; c < 64; ++c) wpack[10240 + o*64+c] = __float2bfloat16(wr2[o*64+c]);
    } else if (tid < 224) {
        const int o = tid - 192;
        for (int c = 0; c < 64; ++c) wpack[12288 + o*64+c] = __float2bfloat16(wlres[o*64+c]);
    } else {
        const int o = tid - 224;
        for (int c = 0; c < 64; ++c) wpack[14336 + o*64+c] = __float2bfloat16(wrres[o*64+c]);
    }
}

// ---------------- fused proj + bidirectional attention ----------------
// LDS: QL[0,32K) QR[32K,64K) VL[64K,80K) VR[80K,96K) X/P[96K,128K) AUX[128K..)
//   q: px-major [256px][64ch] bf16, 16B-block cb at px*8 + (cb^(px&7))
//   v: ch-major [32ch][256px] bf16, 16B-block vb at ch*32 + (vb^(ch&7))
//   P: per-wave 4K, [32 row][64 key] bf16, block pb at row*8 + (pb^(row&7))
#define QL_OFF 0
#define QR_OFF 32768
#define VL_OFF 65536
#define VR_OFF 81920
#define XP_OFF 98304
#define AUX_OFF 131072
#define SMEM_BYTES (131072 + 7680)

__global__ __launch_bounds__(512, 2) void fused_kernel(
    const float* __restrict__ xg_l, const float* __restrict__ xg_r,
    const __hip_bfloat16* __restrict__ wpack, const float* __restrict__ st,
    const float* __restrict__ bqr_g, const float* __restrict__ bl2,
    const float* __restrict__ br2, const float* __restrict__ blres,
    const float* __restrict__ brres, const float* __restrict__ beta,
    const float* __restrict__ gamma, float* __restrict__ out)
{
    __shared__ __align__(16) unsigned char smem[SMEM_BYTES];

    const int bh = blockIdx.x;
    const int b = bh >> 8, h = bh & 255;
    const int tid = threadIdx.x;
    const int wv = tid >> 6, lane = tid & 63;
    const int g = lane >> 4, lr = lane & 15;
    const int px = tid & 255, half = tid >> 8;

    float* aArr  = (float*)(smem + AUX_OFF);          // rstd per px (1K)
    float* bbArr = (float*)(smem + AUX_OFF + 1024);   // -rstd*mu per px (1K)
    float* sArr  = (float*)(smem + AUX_OFF + 2048);
    float* tArr  = (float*)(smem + AUX_OFF + 2304);
    float* bqrA  = (float*)(smem + AUX_OFF + 2560);
    float* bvA   = (float*)(smem + AUX_OFF + 2816);
    float* bresA = (float*)(smem + AUX_OFF + 3072);
    float* coefA = (float*)(smem + AUX_OFF + 3328);
    float* pS    = (float*)(smem + AUX_OFF + 3584);   // 2K
    float* pQ    = (float*)(smem + AUX_OFF + 5632);   // 2K

    const size_t obase = (size_t)b * 64 * HW + (size_t)h * 256;
    const size_t xbase = obase + px;

    // ---- each thread loads 32 channels of both x rows (coalesced) ----
    float xl[32], xr_[32];
#pragma unroll
    for (int c = 0; c < 32; ++c) xl[c] = xg_l[xbase + (size_t)(half*32 + c) * HW];
#pragma unroll
    for (int c = 0; c < 32; ++c) xr_[c] = xg_r[xbase + (size_t)(half*32 + c) * HW];

    if (tid < 64) {
        sArr[tid] = st[tid];
        tArr[tid] = st[64 + tid];
        bqrA[tid] = bqr_g[tid];
        bvA[tid]  = tid < 32 ? bl2[tid]   : br2[tid - 32];
        bresA[tid]= tid < 32 ? blres[tid] : brres[tid - 32];
        coefA[tid]= tid < 32 ? beta[tid]  : gamma[tid - 32];
    }

    // ---- LN partial stats for left row ----
    {
        float s = 0.f, q = 0.f;
#pragma unroll
        for (int c = 0; c < 32; ++c) { s += xl[c]; q = fmaf(xl[c], xl[c], q); }
        pS[half*256 + px] = s;
        pQ[half*256 + px] = q;
    }

    // ---- stage X_left px-major bf16 swizzled (this thread's 32 ch) ----
    uint4* X16 = (uint4*)(smem + XP_OFF);
#pragma unroll
    for (int cb = 0; cb < 4; ++cb) {
        uint4 u;
        u.x = f2bf(xl[cb*8+0]) | ((unsigned)f2bf(xl[cb*8+1]) << 16);
        u.y = f2bf(xl[cb*8+2]) | ((unsigned)f2bf(xl[cb*8+3]) << 16);
        u.z = f2bf(xl[cb*8+4]) | ((unsigned)f2bf(xl[cb*8+5]) << 16);
        u.w = f2bf(xl[cb*8+6]) | ((unsigned)f2bf(xl[cb*8+7]) << 16);
        X16[px*8 + ((half*4 + cb) ^ (px & 7))] = u;
    }
    __syncthreads();
    if (half == 0) {
        float s = pS[px] + pS[256 + px];
        float q = pQ[px] + pQ[256 + px];
        float mu = s * (1.f / 64.f);
        float var = q * (1.f / 64.f) - mu * mu;
        float rstd = rsqrtf(var + 1e-6f);
        aArr[px] = rstd;
        bbArr[px] = -rstd * mu;
    }
    __syncthreads();

    const uint4* W16 = (const uint4*)wpack;

    // proj one side: q (4 Mtiles), v (2), res (2) over this wave's 2 px-tiles
    auto proj_side = [&](int wq, int wvv, int wr, unsigned char* qdst,
                         unsigned char* vdst, int chbase, bool ln) {
        short8 bfr0[2], bfr1[2];
#pragma unroll
        for (int i = 0; i < 2; ++i) {
            int p = (wv*2 + i)*16 + lr;
            bfr0[i] = __builtin_bit_cast(short8, X16[p*8 + (g ^ (p&7))]);
            bfr1[i] = __builtin_bit_cast(short8, X16[p*8 + ((4+g) ^ (p&7))]);
        }
        // ---- q: D[ch][px] ----
#pragma unroll
        for (int ot = 0; ot < 4; ++ot) {
            const int out0 = ot * 16;
            short8 af0 = __builtin_bit_cast(short8, W16[wq + (out0+lr)*8 + g]);
            short8 af1 = __builtin_bit_cast(short8, W16[wq + (out0+lr)*8 + 4 + g]);
            const int ch0 = out0 + 4*g;
            f32x4 c1 = *(const f32x4*)&(ln ? sArr : bqrA)[ch0];
            f32x4 c2 = ln ? *(const f32x4*)&tArr[ch0] : (f32x4){0.f,0.f,0.f,0.f};
#pragma unroll
            for (int i = 0; i < 2; ++i) {
                f32x4 acc = {0.f,0.f,0.f,0.f};
                acc = mfma16(af0, bfr0[i], acc);
                acc = mfma16(af1, bfr1[i], acc);
                const int p = (wv*2+i)*16 + lr;
                float q0,q1,q2,q3;
                if (ln) {
                    const float a_ = aArr[p], b_ = bbArr[p];
                    q0 = fmaf(a_, acc[0], fmaf(b_, c1[0], c2[0]));
                    q1 = fmaf(a_, acc[1], fmaf(b_, c1[1], c2[1]));
                    q2 = fmaf(a_, acc[2], fmaf(b_, c1[2], c2[2]));
                    q3 = fmaf(a_, acc[3], fmaf(b_, c1[3], c2[3]));
                } else {
                    q0 = acc[0]+c1[0]; q1 = acc[1]+c1[1];
                    q2 = acc[2]+c1[2]; q3 = acc[3]+c1[3];
                }
                unsigned lo = f2bf(q0) | ((unsigned)f2bf(q1) << 16);
                unsigned hi = f2bf(q2) | ((unsigned)f2bf(q3) << 16);
                *(uint2*)(qdst + p*128 + (((ch0>>3) ^ (p&7))*16) + (ch0&7)*2)
                    = make_uint2(lo, hi);
            }
        }
        // ---- v: swapped operands -> D[px][ch], 8B store ----
#pragma unroll
        for (int ot = 0; ot < 2; ++ot) {
            const int out0 = ot * 16;
            short8 af0 = __builtin_bit_cast(short8, W16[wvv + (out0+lr)*8 + g]);
            short8 af1 = __builtin_bit_cast(short8, W16[wvv + (out0+lr)*8 + 4 + g]);
            const int ch = out0 + lr;               // this lane's channel
            const float bv = bvA[chbase + ch];
#pragma unroll
            for (int i = 0; i < 2; ++i) {
                f32x4 acc = {0.f,0.f,0.f,0.f};
                acc = mfma16(bfr0[i], af0, acc);
                acc = mfma16(bfr1[i], af1, acc);
                // lane holds px = (wv*2+i)*16 + 4g + r for r=0..3
                unsigned lo = f2bf(acc[0]+bv) | ((unsigned)f2bf(acc[1]+bv) << 16);
                unsigned hi = f2bf(acc[2]+bv) | ((unsigned)f2bf(acc[3]+bv) << 16);
                const int vb = (wv*2+i)*2 + (g>>1);
                *(uint2*)(vdst + ch*512 + ((vb ^ (ch&7))*16) + (g&1)*8)
                    = make_uint2(lo, hi);
            }
        }
        // ---- res -> global: D[ch][px] ----
#pragma unroll
        for (int ot = 0; ot < 2; ++ot) {
            const int out0 = ot * 16;
            short8 af0 = __builtin_bit_cast(short8, W16[wr + (out0+lr)*8 + g]);
            short8 af1 = __builtin_bit_cast(short8, W16[wr + (out0+lr)*8 + 4 + g]);
            const int ch0 = out0 + 4*g;
            f32x4 bz = *(const f32x4*)&bresA[chbase + ch0];
#pragma unroll
            for (int i = 0; i < 2; ++i) {
                f32x4 acc = {0.f,0.f,0.f,0.f};
                acc = mfma16(af0, bfr0[i], acc);
                acc = mfma16(af1, bfr1[i], acc);
                const int p = (wv*2+i)*16 + lr;
                float* op = out + obase + p + (size_t)(chbase + ch0) * HW;
#pragma unroll
                for (int r = 0; r < 4; ++r) op[(size_t)r * HW] = acc[r] + bz[r];
            }
        }
    };

    proj_side(0, 1024, 1536, smem + QL_OFF, smem + VL_OFF, 0, true);
    __syncthreads();

    // ---- stage X_right ----
#pragma unroll
    for (int cb = 0; cb < 4; ++cb) {
        uint4 u;
        u.x = f2bf(xr_[cb*8+0]) | ((unsigned)f2bf(xr_[cb*8+1]) << 16);
        u.y = f2bf(xr_[cb*8+2]) | ((unsigned)f2bf(xr_[cb*8+3]) << 16);
        u.z = f2bf(xr_[cb*8+4]) | ((unsigned)f2bf(xr_[cb*8+5]) << 16);
        u.w = f2bf(xr_[cb*8+6]) | ((unsigned)f2bf(xr_[cb*8+7]) << 16);
        X16[px*8 + ((half*4 + cb) ^ (px & 7))] = u;
    }
    __syncthreads();

    proj_side(512, 1280, 1792, smem + QR_OFF, smem + VR_OFF, 32, false);
    __syncthreads();   // all q/v in LDS, res stores issued; X region becomes P

    // ---- attention: each wave owns 32 query rows (2 groups of 16) per dir ----
    unsigned char* Pw = smem + XP_OFF + wv * 4096;   // [32 row][64 key] quarter
    const float cs = 0.125f * 1.44269504088896f;     // scale * log2(e)

    for (int dir = 0; dir < 2; ++dir) {
        const uint4* Q16 = (const uint4*)(smem + (dir ? QR_OFF : QL_OFF));
        const uint4* K16 = (const uint4*)(smem + (dir ? QL_OFF : QR_OFF));
        const uint4* V16 = (const uint4*)(smem + (dir ? VL_OFF : VR_OFF));
        const float* coef = coefA + dir * 32;

        const int rowA = wv*32 + lr;      // group A: rows wv*32 .. +15
        const int rowB = rowA + 16;       // group B: rows wv*32+16 .. +31
        short8 qA0 = __builtin_bit_cast(short8, Q16[rowA*8 + (g ^ (rowA&7))]);
        short8 qA1 = __builtin_bit_cast(short8, Q16[rowA*8 + ((4+g) ^ (rowA&7))]);
        short8 qB0 = __builtin_bit_cast(short8, Q16[rowB*8 + (g ^ (rowB&7))]);
        short8 qB1 = __builtin_bit_cast(short8, Q16[rowB*8 + ((4+g) ^ (rowB&7))]);

        f32x4 sA[16], sB[16];
#pragma unroll
        for (int t = 0; t < 16; ++t) {
            sA[t] = (f32x4){0.f,0.f,0.f,0.f};
            sB[t] = (f32x4){0.f,0.f,0.f,0.f};
        }
        __builtin_amdgcn_s_setprio(1);
#pragma unroll
        for (int t = 0; t < 16; ++t) {
            const int key = t * 16 + lr;
            const int sw = key & 7;
            short8 a0 = __builtin_bit_cast(short8, K16[key*8 + (g ^ sw)]);
            short8 a1 = __builtin_bit_cast(short8, K16[key*8 + ((4+g) ^ sw)]);
            sA[t] = mfma16(a0, qA0, sA[t]);
            sA[t] = mfma16(a1, qA1, sA[t]);
            sB[t] = mfma16(a0, qB0, sB[t]);
            sB[t] = mfma16(a1, qB1, sB[t]);
        }
        __builtin_amdgcn_s_setprio(0);
        // lane holds S^T[key = 16t + 4g + r][q-row = lr (A) / 16+lr (B)]
        float mA = -3.0e38f, mB = -3.0e38f;
#pragma unroll
        for (int t = 0; t < 16; ++t) {
            mA = fmaxf(mA, fmaxf(fmaxf(sA[t][0], sA[t][1]), fmaxf(sA[t][2], sA[t][3])));
            mB = fmaxf(mB, fmaxf(fmaxf(sB[t][0], sB[t][1]), fmaxf(sB[t][2], sB[t][3])));
        }
        mA = fmaxf(mA, __shfl_xor(mA, 16)); mA = fmaxf(mA, __shfl_xor(mA, 32));
        mB = fmaxf(mB, __shfl_xor(mB, 16)); mB = fmaxf(mB, __shfl_xor(mB, 32));

        float lA = 0.f, lB = 0.f;
        f32x4 oA0 = (f32x4){0.f,0.f,0.f,0.f}, oA1 = (f32x4){0.f,0.f,0.f,0.f};
        f32x4 oB0 = (f32x4){0.f,0.f,0.f,0.f}, oB1 = (f32x4){0.f,0.f,0.f,0.f};
#pragma unroll
        for (int hh = 0; hh < 4; ++hh) {
            // exp + pack + write this quarter's P (32 rows x 64 keys, 4K)
#pragma unroll
            for (int t8 = 0; t8 < 4; ++t8) {
                const int t16 = hh * 4 + t8;
                const int pb = (2*t8 + (g >> 1)) ^ (lr & 7);
                {
                    float p0 = exp2f((sA[t16][0] - mA) * cs);
                    float p1 = exp2f((sA[t16][1] - mA) * cs);
                    float p2 = exp2f((sA[t16][2] - mA) * cs);
                    float p3 = exp2f((sA[t16][3] - mA) * cs);
                    lA += (p0 + p1) + (p2 + p3);
                    unsigned lo = f2bf(p0) | ((unsigned)f2bf(p1) << 16);
                    unsigned hi = f2bf(p2) | ((unsigned)f2bf(p3) << 16);
                    *(uint2*)(Pw + lr*128 + pb*16 + (g & 1)*8) = make_uint2(lo, hi);
                }
                {
                    float p0 = exp2f((sB[t16][0] - mB) * cs);
                    float p1 = exp2f((sB[t16][1] - mB) * cs);
                    float p2 = exp2f((sB[t16][2] - mB) * cs);
                    float p3 = exp2f((sB[t16][3] - mB) * cs);
                    lB += (p0 + p1) + (p2 + p3);
                    unsigned lo = f2bf(p0) | ((unsigned)f2bf(p1) << 16);
                    unsigned hi = f2bf(p2) | ((unsigned)f2bf(p3) << 16);
                    *(uint2*)(Pw + (16+lr)*128 + pb*16 + (g & 1)*8) = make_uint2(lo, hi);
                }
            }
            // PV over this quarter's 64 keys; V fragments shared by both groups
#pragma unroll
            for (int t = 0; t < 2; ++t) {
                const int pb = 4*t + g;
                const int vb = 8*hh + 4*t + g;
                short8 paA = __builtin_bit_cast(short8,
                             *(const uint4*)(Pw + lr*128 + ((pb ^ (lr&7))*16)));
                short8 paB = __builtin_bit_cast(short8,
                             *(const uint4*)(Pw + (16+lr)*128 + ((pb ^ (lr&7))*16)));
                short8 v0 = __builtin_bit_cast(short8, V16[lr*32 + (vb ^ (lr&7))]);
                short8 v1 = __builtin_bit_cast(short8, V16[(16+lr)*32 + (vb ^ (lr&7))]);
                oA0 = mfma16(paA, v0, oA0);
                oA1 = mfma16(paA, v1, oA1);
                oB0 = mfma16(paB, v0, oB0);
                oB1 = mfma16(paB, v1, oB1);
            }
        }
        lA += __shfl_xor(lA, 16); lA += __shfl_xor(lA, 32);
        lB += __shfl_xor(lB, 16); lB += __shfl_xor(lB, 32);
        const float invA = 1.f / lA, invB = 1.f / lB;

        // transpose O through (dead) P, two 16-ch passes per group
        float* Ot = (float*)Pw;   // [16 ch][17] f32 = 1088B <= 4096B
        float* outpA = out + obase + (size_t)(dir*32) * HW + wv*32 + lr;
        float* outpB = outpA + 16;
#pragma unroll
        for (int r = 0; r < 4; ++r) Ot[lr*17 + (g*4 + r)] = oA0[r];
#pragma unroll
        for (int it = 0; it < 4; ++it) {
            const int ch = it*4 + g;
            outpA[(size_t)ch * HW] += Ot[ch*17 + lr] * invA * coef[ch];
        }
#pragma unroll
        for (int r = 0; r < 4; ++r) Ot[lr*17 + (g*4 + r)] = oA1[r];
#pragma unroll
        for (int it = 0; it < 4; ++it) {
            const int ch = it*4 + g;
            outpA[(size_t)(16 + ch) * HW] += Ot[ch*17 + lr] * invA * coef[16 + ch];
        }
#pragma unroll
        for (int r = 0; r < 4; ++r) Ot[lr*17 + (g*4 + r)] = oB0[r];
#pragma unroll
        for (int it = 0; it < 4; ++it) {
            const int ch = it*4 + g;
            outpB[(size_t)ch * HW] += Ot[ch*17 + lr] * invB * coef[ch];
        }
#pragma unroll
        for (int r = 0; r < 4; ++r) Ot[lr*17 + (g*4 + r)] = oB1[r];
#pragma unroll
        for (int it = 0; it < 4; ++it) {
            const int ch = it*4 + g;
            outpB[(size_t)(16 + ch) * HW] += Ot[ch*17 + lr] * invB * coef[16 + ch];
        }
    }
}

extern "C" void kernel_launch(void* const* d_in, const int* in_sizes, int n_in,
                              void* d_out, int out_size, void* d_ws, size_t ws_size,
                              hipStream_t stream) {
    (void)in_sizes; (void)n_in; (void)out_size; (void)ws_size;
    const float* xr    = (const float*)d_in[0];
    const float* xh    = (const float*)d_in[1];
    const float* lnw   = (const float*)d_in[2];
    const float* lnb   = (const float*)d_in[3];
    const float* wl1   = (const float*)d_in[4];
    const float* bl1   = (const float*)d_in[5];
    const float* wr1   = (const float*)d_in[6];
    const float* br1   = (const float*)d_in[7];
    const float* wl2   = (const float*)d_in[8];
    const float* bl2   = (const float*)d_in[9];
    const float* wr2   = (const float*)d_in[10];
    const float* br2   = (const float*)d_in[11];
    const float* wlres = (const float*)d_in[12];
    const float* blres = (const float*)d_in[13];
    const float* wrres = (const float*)d_in[14];
    const float* brres = (const float*)d_in[15];
    const float* beta  = (const float*)d_in[16];
    const float* gamma = (const float*)d_in[17];
    float* out = (float*)d_out;

    __hip_bfloat16* wpack = (__hip_bfloat16*)d_ws;
    float* st = (float*)((unsigned char*)d_ws + 32768);

    prep_kernel<<<dim3(1), dim3(256), 0, stream>>>(
        wl1, bl1, wr1, wl2, wr2, wlres, wrres, lnw, lnb, wpack, st);
    fused_kernel<<<dim3(1024), dim3(512), 0, stream>>>(
        xr, xh, wpack, st, br1, bl2, br2, blres, brres, beta, gamma, out);
}